// Round 1
// baseline (336.522 us; speedup 1.0000x reference)
//
#include <hip/hip_runtime.h>

// SpatialTransform: fused meshgrid + flow displacement + bilinear grid_sample
// (align_corners=True, padding_mode='border').
// B=16, C=4, H=W=512, fp32.
// d_out = [ sample_grid (B*H*W*2 floats) | warped (B*C*H*W floats) ]

#define HW   512
#define BATCH 16
#define CH     4

__global__ __launch_bounds__(256) void spatial_transform_kernel(
    const float*  __restrict__ img,      // [B,C,H,W]
    const float2* __restrict__ flow,     // [B,H,W] of (flow_h, flow_w)
    float2*       __restrict__ grid_out, // [B,H,W] of (gx, gy)
    float*        __restrict__ warped)   // [B,C,H,W]
{
    const int tid = blockIdx.x * blockDim.x + threadIdx.x;  // 0 .. B*H*W-1
    const int x = tid & (HW - 1);
    const int y = (tid >> 9) & (HW - 1);
    const int b = tid >> 18;

    // flow[...,0] adds to grid_h (y), flow[...,1] adds to grid_w (x)
    const float2 f = flow[tid];
    const float scale = 2.0f / 511.0f;   // linspace(-1,1,512) step
    const float gy = fmaf((float)y, scale, -1.0f) + f.x;
    const float gx = fmaf((float)x, scale, -1.0f) + f.y;

    // sample_grid = stack((disp_w, disp_h)) -> (gx, gy)
    grid_out[tid] = make_float2(gx, gy);

    // un-normalize (align_corners=True) + border clamp
    float xs = (gx + 1.0f) * 0.5f * 511.0f;
    float ys = (gy + 1.0f) * 0.5f * 511.0f;
    xs = fminf(fmaxf(xs, 0.0f), 511.0f);
    ys = fminf(fmaxf(ys, 0.0f), 511.0f);

    const float x0f = floorf(xs);
    const float y0f = floorf(ys);
    const float wx = xs - x0f;
    const float wy = ys - y0f;
    const int x0 = (int)x0f;
    const int y0 = (int)y0f;
    const int x1 = min(x0 + 1, HW - 1);
    const int y1 = min(y0 + 1, HW - 1);

    const float w00 = (1.0f - wx) * (1.0f - wy);
    const float w01 = wx * (1.0f - wy);
    const float w10 = (1.0f - wx) * wy;
    const float w11 = wx * wy;

    const int o00 = y0 * HW + x0;
    const int o01 = y0 * HW + x1;
    const int o10 = y1 * HW + x0;
    const int o11 = y1 * HW + x1;

    const float* ib = img    + (size_t)b * CH * (HW * HW);
    float*       wb = warped + (size_t)b * CH * (HW * HW) + y * HW + x;

#pragma unroll
    for (int c = 0; c < CH; ++c) {
        const float* p = ib + c * (HW * HW);
        const float v = p[o00] * w00 + p[o01] * w01 + p[o10] * w10 + p[o11] * w11;
        wb[c * (HW * HW)] = v;
    }
}

extern "C" void kernel_launch(void* const* d_in, const int* in_sizes, int n_in,
                              void* d_out, int out_size, void* d_ws, size_t ws_size,
                              hipStream_t stream) {
    const float*  img  = (const float*)d_in[0];
    const float2* flow = (const float2*)d_in[1];

    float2* grid_out = (float2*)d_out;                                   // B*H*W float2
    float*  warped   = (float*)d_out + (size_t)BATCH * HW * HW * 2;      // B*C*H*W floats

    const int n = BATCH * HW * HW;            // 4,194,304 threads
    spatial_transform_kernel<<<n / 256, 256, 0, stream>>>(img, flow, grid_out, warped);
}

// Round 2
// 251.653 us; speedup vs baseline: 1.3372x; 1.3372x over previous
//
#include <hip/hip_runtime.h>

// SpatialTransform: fused meshgrid + flow displacement + bilinear grid_sample
// (align_corners=True, padding_mode='border').
// B=16, C=4, H=W=512, fp32.
// d_out = [ sample_grid (B*H*W*2 floats) | warped (B*C*H*W floats) ]
//
// R1: two-pass. Pass 1 transposes img [B,C,H,W] -> [B,H,W,C] (float4/pixel)
// into d_ws so the scattered bilinear gather needs 4 float4 loads per pixel
// instead of 16 scalar loads (4x fewer divergent cache-line transactions —
// R0 was transaction-limited, not BW-limited: 16% HBM, 5% VALU, 86% occ).

#define HW    512
#define BATCH 16
#define CH     4

// Pass 1: [B,C,H,W] -> [B,H,W,C]. Reads: 4 coalesced streams. Write: float4 coalesced.
__global__ __launch_bounds__(256) void transpose_chw_hwc(
    const float* __restrict__ img,   // [B,C,H,W]
    float4*      __restrict__ timg)  // [B,H,W] of (c0,c1,c2,c3)
{
    const int tid = blockIdx.x * blockDim.x + threadIdx.x;  // 0 .. B*H*W-1
    const int px = tid & (HW * HW - 1);
    const int b  = tid >> 18;
    const float* ib = img + (size_t)b * CH * (HW * HW) + px;
    float4 v;
    v.x = ib[0 * (HW * HW)];
    v.y = ib[1 * (HW * HW)];
    v.z = ib[2 * (HW * HW)];
    v.w = ib[3 * (HW * HW)];
    timg[tid] = v;
}

// Pass 2: grid + gather from transposed image.
__global__ __launch_bounds__(256) void spatial_transform_hwc(
    const float4* __restrict__ timg,     // [B,H,W,C]
    const float2* __restrict__ flow,     // [B,H,W] of (flow_h, flow_w)
    float2*       __restrict__ grid_out, // [B,H,W] of (gx, gy)
    float*        __restrict__ warped)   // [B,C,H,W]
{
    const int tid = blockIdx.x * blockDim.x + threadIdx.x;
    const int x = tid & (HW - 1);
    const int y = (tid >> 9) & (HW - 1);
    const int b = tid >> 18;

    const float2 f = flow[tid];
    const float scale = 2.0f / 511.0f;
    const float gy = fmaf((float)y, scale, -1.0f) + f.x;
    const float gx = fmaf((float)x, scale, -1.0f) + f.y;

    grid_out[tid] = make_float2(gx, gy);

    float xs = (gx + 1.0f) * 0.5f * 511.0f;
    float ys = (gy + 1.0f) * 0.5f * 511.0f;
    xs = fminf(fmaxf(xs, 0.0f), 511.0f);
    ys = fminf(fmaxf(ys, 0.0f), 511.0f);

    const float x0f = floorf(xs);
    const float y0f = floorf(ys);
    const float wx = xs - x0f;
    const float wy = ys - y0f;
    const int x0 = (int)x0f;
    const int y0 = (int)y0f;
    const int x1 = min(x0 + 1, HW - 1);
    const int y1 = min(y0 + 1, HW - 1);

    const float w00 = (1.0f - wx) * (1.0f - wy);
    const float w01 = wx * (1.0f - wy);
    const float w10 = (1.0f - wx) * wy;
    const float w11 = wx * wy;

    const float4* tb = timg + (size_t)b * (HW * HW);
    const float4 v00 = tb[y0 * HW + x0];
    const float4 v01 = tb[y0 * HW + x1];
    const float4 v10 = tb[y1 * HW + x0];
    const float4 v11 = tb[y1 * HW + x1];

    float*       wb = warped + (size_t)b * CH * (HW * HW) + y * HW + x;
    wb[0 * (HW * HW)] = v00.x * w00 + v01.x * w01 + v10.x * w10 + v11.x * w11;
    wb[1 * (HW * HW)] = v00.y * w00 + v01.y * w01 + v10.y * w10 + v11.y * w11;
    wb[2 * (HW * HW)] = v00.z * w00 + v01.z * w01 + v10.z * w10 + v11.z * w11;
    wb[3 * (HW * HW)] = v00.w * w00 + v01.w * w01 + v10.w * w10 + v11.w * w11;
}

// Fallback (R0 path) if workspace is too small for the transposed image.
__global__ __launch_bounds__(256) void spatial_transform_chw(
    const float*  __restrict__ img,
    const float2* __restrict__ flow,
    float2*       __restrict__ grid_out,
    float*        __restrict__ warped)
{
    const int tid = blockIdx.x * blockDim.x + threadIdx.x;
    const int x = tid & (HW - 1);
    const int y = (tid >> 9) & (HW - 1);
    const int b = tid >> 18;

    const float2 f = flow[tid];
    const float scale = 2.0f / 511.0f;
    const float gy = fmaf((float)y, scale, -1.0f) + f.x;
    const float gx = fmaf((float)x, scale, -1.0f) + f.y;

    grid_out[tid] = make_float2(gx, gy);

    float xs = (gx + 1.0f) * 0.5f * 511.0f;
    float ys = (gy + 1.0f) * 0.5f * 511.0f;
    xs = fminf(fmaxf(xs, 0.0f), 511.0f);
    ys = fminf(fmaxf(ys, 0.0f), 511.0f);

    const float x0f = floorf(xs);
    const float y0f = floorf(ys);
    const float wx = xs - x0f;
    const float wy = ys - y0f;
    const int x0 = (int)x0f;
    const int y0 = (int)y0f;
    const int x1 = min(x0 + 1, HW - 1);
    const int y1 = min(y0 + 1, HW - 1);

    const float w00 = (1.0f - wx) * (1.0f - wy);
    const float w01 = wx * (1.0f - wy);
    const float w10 = (1.0f - wx) * wy;
    const float w11 = wx * wy;

    const int o00 = y0 * HW + x0;
    const int o01 = y0 * HW + x1;
    const int o10 = y1 * HW + x0;
    const int o11 = y1 * HW + x1;

    const float* ib = img    + (size_t)b * CH * (HW * HW);
    float*       wb = warped + (size_t)b * CH * (HW * HW) + y * HW + x;

#pragma unroll
    for (int c = 0; c < CH; ++c) {
        const float* p = ib + c * (HW * HW);
        wb[c * (HW * HW)] = p[o00] * w00 + p[o01] * w01 + p[o10] * w10 + p[o11] * w11;
    }
}

extern "C" void kernel_launch(void* const* d_in, const int* in_sizes, int n_in,
                              void* d_out, int out_size, void* d_ws, size_t ws_size,
                              hipStream_t stream) {
    const float*  img  = (const float*)d_in[0];
    const float2* flow = (const float2*)d_in[1];

    float2* grid_out = (float2*)d_out;                                   // B*H*W float2
    float*  warped   = (float*)d_out + (size_t)BATCH * HW * HW * 2;      // B*C*H*W floats

    const int n = BATCH * HW * HW;            // 4,194,304 pixel-threads
    const size_t need = (size_t)n * CH * sizeof(float);  // 64 MiB transposed image

    if (ws_size >= need) {
        float4* timg = (float4*)d_ws;
        transpose_chw_hwc<<<n / 256, 256, 0, stream>>>(img, timg);
        spatial_transform_hwc<<<n / 256, 256, 0, stream>>>(timg, flow, grid_out, warped);
    } else {
        spatial_transform_chw<<<n / 256, 256, 0, stream>>>(img, flow, grid_out, warped);
    }
}

// Round 3
// 245.583 us; speedup vs baseline: 1.3703x; 1.0247x over previous
//
#include <hip/hip_runtime.h>
#include <hip/hip_fp16.h>

// SpatialTransform: fused meshgrid + flow displacement + bilinear grid_sample
// (align_corners=True, padding_mode='border'). B=16, C=4, H=W=512, fp32.
// d_out = [ sample_grid (B*H*W*2 floats) | warped (B*C*H*W floats) ]
//
// R2: fp16 HWC image in TWO shifted copies so any adjacent x-pair (x0,x0+1)
// is ONE 16B-aligned load. copyA slot s = pixels (2s,2s+1); copyB slot s =
// pixels (2s+1,2s+2), slot 255 border-replicated. Gathers: 2 loads/pixel
// (was 4), half the line traffic. Main kernel processes 2 pixels/thread to
// halve coalesced-path address counts (flow float4, grid float4, warped
// float2/channel). R1 evidence: 33% HBM, 8% VALU, 75% occ -> TA/L1
// transaction-limited; this halves addresses AND bytes on the gather path.

#define HW    512
#define BATCH 16
#define CH     4
#define HWHW  (HW * HW)

union H4 { uint2 u; __half2 h[2]; };   // one pixel: 4 channels fp16
union Q  { uint4 u; __half2 h[4]; };   // one slot: 2 pixels x 4 channels fp16

// Pass 1: [B,C,H,W] fp32 -> two fp16 HWC copies (8B/pixel each).
__global__ __launch_bounds__(256) void transpose_fp16_dual(
    const float* __restrict__ img,
    uint2* __restrict__ copyA,   // [B][H][W] half4: pixel x at slot x
    uint2* __restrict__ copyB)   // [B][H][W] half4: pixel x at slot x-1; slot 511 = px511 replicate
{
    const int tid = blockIdx.x * blockDim.x + threadIdx.x;  // 0 .. B*H*W-1
    const int x  = tid & (HW - 1);
    const int px = tid & (HWHW - 1);
    const int b  = tid >> 18;

    const float* ib = img + (size_t)b * CH * HWHW + px;
    H4 v;
    v.h[0] = __floats2half2_rn(ib[0 * HWHW], ib[1 * HWHW]);
    v.h[1] = __floats2half2_rn(ib[2 * HWHW], ib[3 * HWHW]);

    const size_t base = (size_t)b * HWHW;
    copyA[base + px] = v.u;
    if (x >= 1)      copyB[base + px - 1] = v.u;  // pixel x -> slot x-1 (same row)
    if (x == HW - 1) copyB[base + px]     = v.u;  // border replicate: "pixel 512" := pixel 511
}

// Bilinear gather of 4 channels at (gx,gy) from the dual-copy fp16 image.
__device__ __forceinline__ float4 sample4(const uint4* __restrict__ A,
                                          const uint4* __restrict__ B,
                                          float gx, float gy)
{
    float xs = fminf(fmaxf((gx + 1.0f) * 0.5f * 511.0f, 0.0f), 511.0f);
    float ys = fminf(fmaxf((gy + 1.0f) * 0.5f * 511.0f, 0.0f), 511.0f);
    const float x0f = floorf(xs);
    const float y0f = floorf(ys);
    const float wx = xs - x0f;
    const float wy = ys - y0f;
    const int x0 = (int)x0f;
    const int y0 = (int)y0f;
    const int y1 = min(y0 + 1, HW - 1);

    // pair (x0, x0+1) is one aligned 16B slot in copy (x0&1); x0+1==512 case
    // is the border-replicated slot, matching x1=min(x0+1,511) w/ wx==0.
    const uint4* base = (x0 & 1) ? B : A;
    const int slot = x0 >> 1;
    Q r0, r1;
    r0.u = base[y0 * (HW / 2) + slot];   // row y0: (v00 | v01)
    r1.u = base[y1 * (HW / 2) + slot];   // row y1: (v10 | v11)

    const float w00 = (1.0f - wx) * (1.0f - wy);
    const float w01 = wx * (1.0f - wy);
    const float w10 = (1.0f - wx) * wy;
    const float w11 = wx * wy;

    float4 o;
    o.x = w00 * __low2float (r0.h[0]) + w01 * __low2float (r0.h[2])
        + w10 * __low2float (r1.h[0]) + w11 * __low2float (r1.h[2]);
    o.y = w00 * __high2float(r0.h[0]) + w01 * __high2float(r0.h[2])
        + w10 * __high2float(r1.h[0]) + w11 * __high2float(r1.h[2]);
    o.z = w00 * __low2float (r0.h[1]) + w01 * __low2float (r0.h[3])
        + w10 * __low2float (r1.h[1]) + w11 * __low2float (r1.h[3]);
    o.w = w00 * __high2float(r0.h[1]) + w01 * __high2float(r0.h[3])
        + w10 * __high2float(r1.h[1]) + w11 * __high2float(r1.h[3]);
    return o;
}

// Pass 2: 2 adjacent output pixels per thread.
__global__ __launch_bounds__(256) void spatial_transform_fp16(
    const uint4* __restrict__ copyA,  // [B][H][256] slots
    const uint4* __restrict__ copyB,  // [B][H][256] slots
    const float4* __restrict__ flow4, // [B*H*W/2]: (fh0,fw0,fh1,fw1)
    float4* __restrict__ grid4,       // [B*H*W/2]: (gx0,gy0,gx1,gy1)
    float*  __restrict__ warped)      // [B,C,H,W]
{
    const int tid = blockIdx.x * blockDim.x + threadIdx.x;  // 0 .. B*H*W/2-1
    const int x = (tid & (HW / 2 - 1)) << 1;
    const int y = (tid >> 8) & (HW - 1);
    const int b = tid >> 17;

    const float4 f = flow4[tid];
    const float scale = 2.0f / 511.0f;
    const float by  = fmaf((float)y, scale, -1.0f);
    const float gy0 = by + f.x;                              // flow[...,0] -> y
    const float gx0 = fmaf((float)x, scale, -1.0f) + f.y;    // flow[...,1] -> x
    const float gy1 = by + f.z;
    const float gx1 = fmaf((float)(x + 1), scale, -1.0f) + f.w;

    grid4[tid] = make_float4(gx0, gy0, gx1, gy1);

    const uint4* A = copyA + (size_t)b * (HW * (HW / 2));
    const uint4* B = copyB + (size_t)b * (HW * (HW / 2));
    const float4 s0 = sample4(A, B, gx0, gy0);
    const float4 s1 = sample4(A, B, gx1, gy1);

    float2* wb = (float2*)(warped + (size_t)b * CH * HWHW + y * HW + x);
    wb[0 * (HWHW / 2)] = make_float2(s0.x, s1.x);
    wb[1 * (HWHW / 2)] = make_float2(s0.y, s1.y);
    wb[2 * (HWHW / 2)] = make_float2(s0.z, s1.z);
    wb[3 * (HWHW / 2)] = make_float2(s0.w, s1.w);
}

// Fallback (R0 path) if workspace is too small.
__global__ __launch_bounds__(256) void spatial_transform_chw(
    const float*  __restrict__ img,
    const float2* __restrict__ flow,
    float2*       __restrict__ grid_out,
    float*        __restrict__ warped)
{
    const int tid = blockIdx.x * blockDim.x + threadIdx.x;
    const int x = tid & (HW - 1);
    const int y = (tid >> 9) & (HW - 1);
    const int b = tid >> 18;

    const float2 f = flow[tid];
    const float scale = 2.0f / 511.0f;
    const float gy = fmaf((float)y, scale, -1.0f) + f.x;
    const float gx = fmaf((float)x, scale, -1.0f) + f.y;
    grid_out[tid] = make_float2(gx, gy);

    float xs = fminf(fmaxf((gx + 1.0f) * 0.5f * 511.0f, 0.0f), 511.0f);
    float ys = fminf(fmaxf((gy + 1.0f) * 0.5f * 511.0f, 0.0f), 511.0f);
    const float x0f = floorf(xs), y0f = floorf(ys);
    const float wx = xs - x0f, wy = ys - y0f;
    const int x0 = (int)x0f, y0 = (int)y0f;
    const int x1 = min(x0 + 1, HW - 1), y1 = min(y0 + 1, HW - 1);
    const float w00 = (1.0f - wx) * (1.0f - wy), w01 = wx * (1.0f - wy);
    const float w10 = (1.0f - wx) * wy,          w11 = wx * wy;
    const int o00 = y0 * HW + x0, o01 = y0 * HW + x1;
    const int o10 = y1 * HW + x0, o11 = y1 * HW + x1;
    const float* ib = img    + (size_t)b * CH * HWHW;
    float*       wb = warped + (size_t)b * CH * HWHW + y * HW + x;
#pragma unroll
    for (int c = 0; c < CH; ++c) {
        const float* p = ib + c * HWHW;
        wb[c * HWHW] = p[o00] * w00 + p[o01] * w01 + p[o10] * w10 + p[o11] * w11;
    }
}

extern "C" void kernel_launch(void* const* d_in, const int* in_sizes, int n_in,
                              void* d_out, int out_size, void* d_ws, size_t ws_size,
                              hipStream_t stream) {
    const float* img  = (const float*)d_in[0];
    const void*  flow = d_in[1];

    float* grid_out = (float*)d_out;                                  // B*H*W*2 floats
    float* warped   = (float*)d_out + (size_t)BATCH * HWHW * 2;       // B*C*H*W floats

    const int n_px = BATCH * HWHW;                       // 4,194,304 pixels
    const size_t copy_bytes = (size_t)n_px * 8;          // 32 MiB per fp16 copy
    const size_t need = 2 * copy_bytes;                  // 64 MiB

    if (ws_size >= need) {
        uint2* copyA = (uint2*)d_ws;
        uint2* copyB = (uint2*)((char*)d_ws + copy_bytes);
        transpose_fp16_dual<<<n_px / 256, 256, 0, stream>>>(img, copyA, copyB);
        spatial_transform_fp16<<<(n_px / 2) / 256, 256, 0, stream>>>(
            (const uint4*)copyA, (const uint4*)copyB,
            (const float4*)flow, (float4*)grid_out, warped);
    } else {
        spatial_transform_chw<<<n_px / 256, 256, 0, stream>>>(
            img, (const float2*)flow, (float2*)grid_out, warped);
    }
}

// Round 4
// 225.414 us; speedup vs baseline: 1.4929x; 1.0895x over previous
//
#include <hip/hip_runtime.h>
#include <hip/hip_fp16.h>

// SpatialTransform: fused meshgrid + flow displacement + bilinear grid_sample
// (align_corners=True, padding_mode='border'). B=16, C=4, H=W=512, fp32.
// d_out = [ sample_grid (B*H*W*2 floats) | warped (B*C*H*W floats) ]
//
// R3: R2's dual fp16 HWC copies (any (x0,x0+1) pair = ONE 16B load; 2
// gather loads/pixel) + XCD slab swizzle: blocks dispatch round-robin over
// 8 XCDs, so decode blockIdx as (xcd = j&7) and give each XCD contiguous
// 256-row slabs of one batch, rows in order. Hot gather window per slab
// (~±60-row apron, A+B) ~2.9 MB < 4 MiB per-XCD L2 -> each image line
// fetched ~once from HBM. R2 evidence: FETCH 264 MB (3.6x gather
// amplification), 50% HBM -> L2-residency-limited, not transactions.

#define HW    512
#define BATCH 16
#define CH     4
#define HWHW  (HW * HW)

union H4 { uint2 u; __half2 h[2]; };   // one pixel: 4 channels fp16
union Q  { uint4 u; __half2 h[4]; };   // one slot: 2 pixels x 4 channels fp16

// Pass 1: [B,C,H,W] fp32 -> two fp16 HWC copies. 2 pixels/thread.
// copyA slot p = pixel p. copyB slot p = pixel p+1 (slot 511 = pixel 511).
__global__ __launch_bounds__(256) void transpose_fp16_dual(
    const float2* __restrict__ img2,
    uint2* __restrict__ copyA,
    uint2* __restrict__ copyB)
{
    const int t = blockIdx.x * blockDim.x + threadIdx.x;  // 0 .. B*H*W/2-1
    const int s = t & (HWHW / 2 - 1);     // pixel-pair index within image
    const int b = t >> 17;

    const float2* ib = img2 + (size_t)b * CH * (HWHW / 2) + s;
    const float2 c0 = ib[0 * (HWHW / 2)];
    const float2 c1 = ib[1 * (HWHW / 2)];
    const float2 c2 = ib[2 * (HWHW / 2)];
    const float2 c3 = ib[3 * (HWHW / 2)];

    H4 v0, v1;                             // pixels 2s, 2s+1
    v0.h[0] = __floats2half2_rn(c0.x, c1.x);
    v0.h[1] = __floats2half2_rn(c2.x, c3.x);
    v1.h[0] = __floats2half2_rn(c0.y, c1.y);
    v1.h[1] = __floats2half2_rn(c2.y, c3.y);

    const size_t base = (size_t)b * HWHW;
    const int px0 = s << 1;               // even pixel index within image
    const int x0  = px0 & (HW - 1);       // even x

    // A: aligned 16B store of both pixels
    Q a; a.u.x = v0.u.x; a.u.y = v0.u.y; a.u.z = v1.u.x; a.u.w = v1.u.y;
    ((uint4*)copyA)[(base + px0) >> 1] = a.u;

    // B: pixel p -> slot p-1 (same row); slot 511 replicates pixel 511
    if (x0 != 0)      copyB[base + px0 - 1] = v0.u;
    copyB[base + px0] = v1.u;
    if (x0 == HW - 2) copyB[base + px0 + 1] = v1.u;
}

// Bilinear gather of 4 channels at (gx,gy) from the dual-copy fp16 image.
__device__ __forceinline__ float4 sample4(const uint4* __restrict__ A,
                                          const uint4* __restrict__ B,
                                          float gx, float gy)
{
    float xs = fminf(fmaxf((gx + 1.0f) * 0.5f * 511.0f, 0.0f), 511.0f);
    float ys = fminf(fmaxf((gy + 1.0f) * 0.5f * 511.0f, 0.0f), 511.0f);
    const float x0f = floorf(xs);
    const float y0f = floorf(ys);
    const float wx = xs - x0f;
    const float wy = ys - y0f;
    const int x0 = (int)x0f;
    const int y0 = (int)y0f;
    const int y1 = min(y0 + 1, HW - 1);

    const uint4* base = (x0 & 1) ? B : A;
    const int slot = x0 >> 1;
    Q r0, r1;
    r0.u = base[y0 * (HW / 2) + slot];   // row y0: (v00 | v01)
    r1.u = base[y1 * (HW / 2) + slot];   // row y1: (v10 | v11)

    const float w00 = (1.0f - wx) * (1.0f - wy);
    const float w01 = wx * (1.0f - wy);
    const float w10 = (1.0f - wx) * wy;
    const float w11 = wx * wy;

    float4 o;
    o.x = w00 * __low2float (r0.h[0]) + w01 * __low2float (r0.h[2])
        + w10 * __low2float (r1.h[0]) + w11 * __low2float (r1.h[2]);
    o.y = w00 * __high2float(r0.h[0]) + w01 * __high2float(r0.h[2])
        + w10 * __high2float(r1.h[0]) + w11 * __high2float(r1.h[2]);
    o.z = w00 * __low2float (r0.h[1]) + w01 * __low2float (r0.h[3])
        + w10 * __low2float (r1.h[1]) + w11 * __low2float (r1.h[3]);
    o.w = w00 * __high2float(r0.h[1]) + w01 * __high2float(r0.h[3])
        + w10 * __high2float(r1.h[1]) + w11 * __high2float(r1.h[3]);
    return o;
}

// Pass 2: one block = one row (512 px, 2 px/thread), slab-swizzled to XCDs.
__global__ __launch_bounds__(256) void spatial_transform_fp16(
    const uint4* __restrict__ copyA,
    const uint4* __restrict__ copyB,
    const float4* __restrict__ flow4, // [B*H*W/2]: (fh0,fw0,fh1,fw1)
    float4* __restrict__ grid4,       // [B*H*W/2]: (gx0,gy0,gx1,gy1)
    float*  __restrict__ warped)      // [B,C,H,W]
{
    // XCD slab swizzle: 8192 rows -> 32 slabs of 256 rows; slab%8 = XCD.
    const int j    = blockIdx.x;
    const int xcd  = j & 7;
    const int i    = j >> 3;
    const int slab = ((i >> 8) << 3) | xcd;        // 0..31
    const int r    = (slab << 8) | (i & 255);      // global row 0..8191
    const int b    = r >> 9;
    const int y    = r & (HW - 1);
    const int x    = (int)threadIdx.x << 1;
    const int tid  = r * (HW / 2) + threadIdx.x;   // flow4/grid4 index

    const float4 f = flow4[tid];
    const float scale = 2.0f / 511.0f;
    const float by  = fmaf((float)y, scale, -1.0f);
    const float gy0 = by + f.x;                              // flow[...,0] -> y
    const float gx0 = fmaf((float)x, scale, -1.0f) + f.y;    // flow[...,1] -> x
    const float gy1 = by + f.z;
    const float gx1 = fmaf((float)(x + 1), scale, -1.0f) + f.w;

    grid4[tid] = make_float4(gx0, gy0, gx1, gy1);

    const uint4* A = copyA + (size_t)b * (HW * (HW / 2));
    const uint4* B = copyB + (size_t)b * (HW * (HW / 2));
    const float4 s0 = sample4(A, B, gx0, gy0);
    const float4 s1 = sample4(A, B, gx1, gy1);

    float2* wb = (float2*)(warped + (size_t)b * CH * HWHW + y * HW + x);
    wb[0 * (HWHW / 2)] = make_float2(s0.x, s1.x);
    wb[1 * (HWHW / 2)] = make_float2(s0.y, s1.y);
    wb[2 * (HWHW / 2)] = make_float2(s0.z, s1.z);
    wb[3 * (HWHW / 2)] = make_float2(s0.w, s1.w);
}

// Fallback (R0 path) if workspace is too small.
__global__ __launch_bounds__(256) void spatial_transform_chw(
    const float*  __restrict__ img,
    const float2* __restrict__ flow,
    float2*       __restrict__ grid_out,
    float*        __restrict__ warped)
{
    const int tid = blockIdx.x * blockDim.x + threadIdx.x;
    const int x = tid & (HW - 1);
    const int y = (tid >> 9) & (HW - 1);
    const int b = tid >> 18;

    const float2 f = flow[tid];
    const float scale = 2.0f / 511.0f;
    const float gy = fmaf((float)y, scale, -1.0f) + f.x;
    const float gx = fmaf((float)x, scale, -1.0f) + f.y;
    grid_out[tid] = make_float2(gx, gy);

    float xs = fminf(fmaxf((gx + 1.0f) * 0.5f * 511.0f, 0.0f), 511.0f);
    float ys = fminf(fmaxf((gy + 1.0f) * 0.5f * 511.0f, 0.0f), 511.0f);
    const float x0f = floorf(xs), y0f = floorf(ys);
    const float wx = xs - x0f, wy = ys - y0f;
    const int x0 = (int)x0f, y0 = (int)y0f;
    const int x1 = min(x0 + 1, HW - 1), y1 = min(y0 + 1, HW - 1);
    const float w00 = (1.0f - wx) * (1.0f - wy), w01 = wx * (1.0f - wy);
    const float w10 = (1.0f - wx) * wy,          w11 = wx * wy;
    const int o00 = y0 * HW + x0, o01 = y0 * HW + x1;
    const int o10 = y1 * HW + x0, o11 = y1 * HW + x1;
    const float* ib = img    + (size_t)b * CH * HWHW;
    float*       wb = warped + (size_t)b * CH * HWHW + y * HW + x;
#pragma unroll
    for (int c = 0; c < CH; ++c) {
        const float* p = ib + c * HWHW;
        wb[c * HWHW] = p[o00] * w00 + p[o01] * w01 + p[o10] * w10 + p[o11] * w11;
    }
}

extern "C" void kernel_launch(void* const* d_in, const int* in_sizes, int n_in,
                              void* d_out, int out_size, void* d_ws, size_t ws_size,
                              hipStream_t stream) {
    const float* img  = (const float*)d_in[0];
    const void*  flow = d_in[1];

    float* grid_out = (float*)d_out;                                  // B*H*W*2 floats
    float* warped   = (float*)d_out + (size_t)BATCH * HWHW * 2;       // B*C*H*W floats

    const int n_px = BATCH * HWHW;                       // 4,194,304 pixels
    const size_t copy_bytes = (size_t)n_px * 8;          // 32 MiB per fp16 copy
    const size_t need = 2 * copy_bytes;                  // 64 MiB

    if (ws_size >= need) {
        uint2* copyA = (uint2*)d_ws;
        uint2* copyB = (uint2*)((char*)d_ws + copy_bytes);
        transpose_fp16_dual<<<(n_px / 2) / 256, 256, 0, stream>>>(
            (const float2*)img, copyA, copyB);
        spatial_transform_fp16<<<(n_px / 2) / 256, 256, 0, stream>>>(
            (const uint4*)copyA, (const uint4*)copyB,
            (const float4*)flow, (float4*)grid_out, warped);
    } else {
        spatial_transform_chw<<<n_px / 256, 256, 0, stream>>>(
            img, (const float2*)flow, (float2*)grid_out, warped);
    }
}